// Round 10
// baseline (360.185 us; speedup 1.0000x reference)
//
#include <hip/hip_runtime.h>
#include <cstdint>

#define NN 512
#define EE 64
#define HIDD 256
#define OUTD 32
#define L2E 1.4426950408889634f

#define AS1 __attribute__((address_space(1)))
#define AS3 __attribute__((address_space(3)))

typedef __bf16 bf16x8 __attribute__((ext_vector_type(8)));
typedef float f32x4 __attribute__((ext_vector_type(4)));

// -------- device-global scratch (fully rewritten every call; deterministic) --------
__device__ float g_WhsT[HIDD*EE];      // W_hs transposed [k][e]
__device__ uint4 g_Ag3[4096];          // bf16 A-frags; idx = (kh*16+mh)*64 + lane
__device__ float g_biasI[256];         // [e*4 + gate], gate-scaled
__device__ float g_embW[EE*4];         // per-e embed (a,b,bias,0)
__device__ float g_Wqc[4096];          // Wq2 @ Wq
__device__ float g_Wkc[4096];          // Wk2 @ Wk
__device__ float g_Wvc[4096];          // Wv2 @ Wv
__device__ float g_M2T[4096];          // [c][e] = (L2E/8) sum_a Wkc[a,e] Wqc[a,c]
__device__ float g_cvec[EE];
__device__ float g_Wtot[OUTD*EE];      // W_o @ W_out @ Wvc  (row-major [o][k])
__device__ float g_btot[OUTD];
__device__ float g_hs[NN*EE];
__device__ float g_part[2*NN][68];     // per (b,half): ctx_u[64], m, l

__device__ __forceinline__ float ex2(float x){ return __builtin_amdgcn_exp2f(x); }
__device__ __forceinline__ float rcp_(float x){ return __builtin_amdgcn_rcpf(x); }

__device__ __forceinline__ void bar_lgkm() {
    asm volatile("s_waitcnt lgkmcnt(0)" ::: "memory");
    __builtin_amdgcn_s_barrier();
    __builtin_amdgcn_sched_barrier(0);
}

// ---------------- prepA: frag packing, transposes, combined projections -----
__global__ __launch_bounds__(256) void prepA(
    const float* __restrict__ W_ih, const float* __restrict__ b_ih,
    const float* __restrict__ W_hh, const float* __restrict__ b_hh,
    const float* __restrict__ Wq, const float* __restrict__ Wk, const float* __restrict__ Wv,
    const float* __restrict__ W_in, const float* __restrict__ W_hs,
    const float* __restrict__ W_s, const float* __restrict__ b_s,
    const float* __restrict__ W_v, const float* __restrict__ b_v)
{
    __shared__ float shT[64*65];
    const int blk = blockIdx.x, tid = threadIdx.x;
    if (blk < 4) {
        // A-frags: frag (kh, mh): row r'=lane&15 -> e = 4*mh + (r'>>2), gate = r'&3
#pragma unroll
        for (int ii = 0; ii < 4; ++ii) {
            int idx = blk*1024 + ii*256 + tid;
            int kh = idx >> 10, mh = (idx >> 6) & 15, lane = idx & 63;
            int rp = lane & 15;
            int e = 4*mh + (rp >> 2), gate = rp & 3;
            int o = gate*64 + e;
            int kb = kh*32 + (lane >> 4)*8;
            float sc = (gate == 2) ? (-2.f*L2E) : (-L2E);
            bf16x8 vv;
#pragma unroll
            for (int j = 0; j < 8; ++j) {
                int k = kb + j;
                float raw = (k < 64) ? W_ih[o*64 + k] : W_hh[o*64 + (k - 64)];
                vv[j] = (__bf16)(sc * raw);
            }
            g_Ag3[idx] = __builtin_bit_cast(uint4, vv);
        }
    } else if (blk == 4) {
        {
            int e = tid >> 2, gate = tid & 3, o = gate*64 + e;
            float sc = (gate == 2) ? (-2.f*L2E) : (-L2E);
            g_biasI[tid] = sc * (b_ih[o] + b_hh[o]);
        }
        if (tid < 64) {
            int e = tid;
            if (e < 32) {
                g_embW[e*4+0] = W_s[e*2]; g_embW[e*4+1] = W_s[e*2+1]; g_embW[e*4+2] = b_s[e];
            } else {
                g_embW[e*4+0] = 4.f*W_v[(e-32)*2]; g_embW[e*4+1] = 4.f*W_v[(e-32)*2+1]; g_embW[e*4+2] = b_v[e-32];
            }
            g_embW[e*4+3] = 0.f;
        }
    } else if (blk == 5) {
        // LDS-tiled transpose W_hs [64][256] -> g_WhsT [256][64]
        for (int kt = 0; kt < 4; ++kt) {
            __syncthreads();
#pragma unroll
            for (int i = 0; i < 16; ++i) {
                int row = i*4 + (tid >> 6), col = tid & 63;
                shT[col*65 + row] = W_hs[row*256 + kt*64 + col];
            }
            __syncthreads();
#pragma unroll
            for (int i = 0; i < 16; ++i) {
                int krow = i*4 + (tid >> 6), e = tid & 63;
                g_WhsT[(kt*64 + krow)*64 + e] = shT[krow*65 + e];
            }
        }
    } else {
        // blk 6,7,8: combined projections W?c = W?2 @ W?  (LDS-tiled, parallel)
        const int t = blk - 6;
        const float* W2 = W_in + t*4096;
        const float* W1 = (t == 0) ? Wq : ((t == 1) ? Wk : Wv);
        float* dst = (t == 0) ? g_Wqc : ((t == 1) ? g_Wkc : g_Wvc);
        for (int i = tid; i < 4096; i += 256) shT[i] = W1[i];
        __syncthreads();
        const int c = tid & 63, a0 = (tid >> 6) * 16;
        for (int aa = 0; aa < 16; ++aa) {
            int a = a0 + aa;
            float s = 0.f;
            for (int m = 0; m < 64; ++m) s = fmaf(W2[a*64 + m], shT[m*64 + c], s);
            dst[a*64 + c] = s;
        }
    }
}

// ---------------- prepB: M2T/cvec (blk0), Wtot/btot (blk1), hs rows (2..513) --
__global__ __launch_bounds__(256) void prepB(
    const float* __restrict__ hidden, const float* __restrict__ b_hs,
    const float* __restrict__ b_in, const float* __restrict__ W_out,
    const float* __restrict__ b_out, const float* __restrict__ W_o,
    const float* __restrict__ b_o)
{
    __shared__ float shA[4096];
    __shared__ float shB[4096];
    __shared__ float shS[64];
    const int blk = blockIdx.x, tid = threadIdx.x;
    if (blk == 0) {
        for (int i = tid; i < 4096; i += 256) { shA[i] = g_Wkc[i]; shB[i] = g_Wqc[i]; }
        __syncthreads();
        const int e = tid & 63, c0b = (tid >> 6) * 16;
        for (int cc = 0; cc < 16; ++cc) {
            int c = c0b + cc;
            float s = 0.f;
            for (int a = 0; a < 64; ++a) s = fmaf(shA[a*64 + e], shB[a*64 + c], s);
            g_M2T[c*64 + e] = s * (L2E * 0.125f);
        }
        if (tid < 64) {
            float s = 0.f;
            for (int a = 0; a < 64; ++a) s = fmaf(shA[a*64 + tid], b_in[a], s);
            g_cvec[tid] = s * (L2E * 0.125f);
        }
    } else if (blk == 1) {
        for (int i = tid; i < 4096; i += 256) shA[i] = g_Wvc[i];
        if (tid < 64) {
            float s = 0.f;
            for (int k = 0; k < 64; ++k) s = fmaf(W_out[tid*64 + k], b_in[128 + k], s);
            shS[tid] = s + b_out[tid];
        }
        __syncthreads();
        {   // Wtmp = W_out @ Wvc -> shB
            const int j = tid & 63, i0 = (tid >> 6) * 16;
            for (int ii = 0; ii < 16; ++ii) {
                int i = i0 + ii;
                float s = 0.f;
                for (int k = 0; k < 64; ++k) s = fmaf(W_out[i*64 + k], shA[k*64 + j], s);
                shB[i*64 + j] = s;
            }
        }
        __syncthreads();
        for (int idx = tid; idx < OUTD*64; idx += 256) {
            int o = idx >> 6, j = idx & 63;
            float s = 0.f;
            for (int i = 0; i < 64; ++i) s = fmaf(W_o[o*64 + i], shB[i*64 + j], s);
            g_Wtot[o*64 + j] = s;
        }
        if (tid < OUTD) {
            float s = 0.f;
            for (int i = 0; i < 64; ++i) s = fmaf(W_o[tid*64 + i], shS[i], s);
            g_btot[tid] = s + b_o[tid];
        }
    } else {
        const int b = blk - 2;
        shA[tid] = hidden[b*HIDD + tid];
        __syncthreads();
        const int e = tid & 63, kq = tid >> 6;
        float s = 0.f;
#pragma unroll 8
        for (int k2 = 0; k2 < 64; ++k2) {
            int kk = kq*64 + k2;
            s = fmaf(g_WhsT[kk*64 + e], shA[kk], s);
        }
        shB[kq*64 + e] = s;
        __syncthreads();
        if (tid < 64)
            g_hs[b*64 + tid] = shB[tid] + shB[64+tid] + shB[128+tid] + shB[192+tid] + b_hs[tid];
    }
}

// ---------------- row kernel: 1024 blocks x 256 thr (4 waves), (row, half).
// Wave owns 16 full softmax rows per tile; wave-local softmax; 4 barriers. ----
__global__ __launch_bounds__(256, 3) void row_kernel(
    const float* __restrict__ obs1, const float* __restrict__ obs2,
    const float* __restrict__ h0, const float* __restrict__ c0)
{
    __shared__ __align__(16) float Cs[2][64*64];      // 2 x 16KB, swizzled 256B rows
    __shared__ float2 obs1L[NN], obs2L[NN];           // 8KB
    __shared__ float2 embAB[64];                      // embed (a,b)
    __shared__ float  embC[64];                       // embed bias
    __shared__ __align__(16) float biasL[256];
    __shared__ float hsL[64], qkL[64];
    __shared__ float part[4][64];
    __shared__ float ctxW[4][64];
    __shared__ float mW[4], lW[4];

    const int bh = blockIdx.x, b = bh >> 1, half = bh & 1;
    const int tid = threadIdx.x;
    const int w = tid >> 6, l = tid & 63;
    const int r = l & 15, q8 = l >> 4;

    const size_t rowoff = (size_t)b * NN * EE;
    const float* h0full = h0 + rowoff;
    const float* c0h = c0 + rowoff + (size_t)half * 256 * EE;

    // ---- staging: 4 x global_load_lds (16B) per thread, pre-swizzled source ----
    auto stageC = [&](int t, int buf) {
        const float* gsrc = c0h + (size_t)t * 64 * EE;
#pragma unroll
        for (int j = 0; j < 4; ++j) {
            const int chunk = j*256 + tid;
            const int row = chunk >> 4, col = chunk & 15;
            const char* g = (const char*)gsrc + row*256 + ((col*16) ^ ((row & 15) << 4));
            char* lp = (char*)&Cs[buf][0] + chunk*16;
            __builtin_amdgcn_global_load_lds((const AS1 void*)g, (AS3 void*)lp, 16, 0, 0);
        }
    };

    // ---- prologue ----
    stageC(0, 0);
    obs2L[tid]       = ((const float2*)obs2)[tid];
    obs2L[tid + 256] = ((const float2*)obs2)[tid + 256];
    obs1L[tid]       = ((const float2*)obs1)[tid];
    obs1L[tid + 256] = ((const float2*)obs1)[tid + 256];
    biasL[tid] = g_biasI[tid];
    if (tid < 64) {
        float4 ew = *(const float4*)(g_embW + tid*4);
        embAB[tid] = make_float2(ew.x, ew.y);
        embC[tid]  = ew.z;
        hsL[tid]   = g_hs[b*64 + tid];
    }
    bar_lgkm();
    {   // qk = M2T^T @ hs + cvec  (single matvec, 2 rounds)
        float s = 0.f;
#pragma unroll
        for (int k2 = 0; k2 < 16; ++k2) {
            int kk = w*16 + k2;
            s = fmaf(g_M2T[kk*64 + l], hsL[kk], s);
        }
        part[w][l] = s;
    }
    bar_lgkm();
    if (tid < 64)
        qkL[tid] = part[0][tid] + part[1][tid] + part[2][tid] + part[3][tid] + g_cvec[tid];
    bar_lgkm();
    float qkv[16];
#pragma unroll
    for (int mh = 0; mh < 16; ++mh) qkv[mh] = qkL[4*mh + q8];
    const float2 ob2 = obs2L[b], ob1 = obs1L[b];
    const float velbx = ob2.x - ob1.x, velby = ob2.y - ob1.y;
    asm volatile("s_waitcnt vmcnt(0) lgkmcnt(0)" ::: "memory");   // Cs[0] staged
    __builtin_amdgcn_s_barrier();
    __builtin_amdgcn_sched_barrier(0);

    float m_run = -__builtin_inff(), l_run = 0.f;
    float ctxa[16];
#pragma unroll
    for (int i = 0; i < 16; ++i) ctxa[i] = 0.f;

#pragma unroll 1
    for (int t = 0; t < 4; ++t) {
        const int buf = t & 1;
        if (t < 3) stageC(t + 1, buf ^ 1);
        const int prow = half*256 + t*64 + w*16 + r;   // this lane's pair (softmax row)

        // ---- B-frags: embed in-register (kh 0,1) + H direct (kh 2,3) ----
        bf16x8 Bf[4];
        {
            const float2 o2 = obs2L[prow], o1 = obs1L[prow];
            const float u0s = o2.x - ob2.x, u1s = o2.y - ob2.y;
            const float u0v = (o2.x - o1.x) - velbx, u1v = (o2.y - o1.y) - velby;
#pragma unroll
            for (int j = 0; j < 8; ++j) {
                float2 ab = embAB[q8*8 + j]; float cc = embC[q8*8 + j];
                Bf[0][j] = (__bf16)fmaxf(fmaf(ab.x, u0s, fmaf(ab.y, u1s, cc)), 0.f);
            }
#pragma unroll
            for (int j = 0; j < 8; ++j) {
                float2 ab = embAB[32 + q8*8 + j]; float cc = embC[32 + q8*8 + j];
                Bf[1][j] = (__bf16)fmaxf(fmaf(ab.x, u0v, fmaf(ab.y, u1v, cc)), 0.f);
            }
            const float* hp = h0full + (size_t)prow*EE + q8*8;
            f32x4 f0 = *(const f32x4*)(hp);
            f32x4 f1 = *(const f32x4*)(hp + 4);
            f32x4 f2 = *(const f32x4*)(hp + 32);
            f32x4 f3 = *(const f32x4*)(hp + 36);
#pragma unroll
            for (int i = 0; i < 4; ++i) {
                Bf[2][i] = (__bf16)f0[i]; Bf[2][4+i] = (__bf16)f1[i];
                Bf[3][i] = (__bf16)f2[i]; Bf[3][4+i] = (__bf16)f3[i];
            }
        }

        // ---- 64 MFMA: all 16 m-blocks, A streamed from L1/L2 ----
        f32x4 acc[16];
#pragma unroll
        for (int mh = 0; mh < 16; ++mh) acc[mh] = *(const f32x4*)&biasL[(4*mh + q8)*4];
#pragma unroll
        for (int kh = 0; kh < 4; ++kh)
#pragma unroll
            for (int mh = 0; mh < 16; ++mh) {
                bf16x8 Af = __builtin_bit_cast(bf16x8, g_Ag3[(kh*16 + mh)*64 + l]);
                acc[mh] = __builtin_amdgcn_mfma_f32_16x16x32_bf16(Af, Bf[kh], acc[mh], 0, 0, 0);
            }

        // ---- LSTM elementwise + lane-local score dot ----
        float sp = 0.f;
        float Eev[16];
        const int crow = w*16 + r;
        const float* CsC = &Cs[buf][0];
#pragma unroll
        for (int mh = 0; mh < 16; ++mh) {
            f32x4 g4 = acc[mh];              // (yi, yf, yg, yo), pre-scaled
            float ea = ex2(g4[0]);
            float eg = ex2(g4[2]);
            float itg = (1.f - eg) * rcp_((1.f + ea)*(1.f + eg));   // sig(i)*tanh(g)
            float sf = rcp_(1.f + ex2(g4[1]));
            float cpv = CsC[crow*64 + ((4*mh + q8) ^ (r << 2))];
            float cn = fmaf(sf, cpv, itg);
            float eo = ex2(g4[3]);
            float ec = ex2(-2.f*L2E*cn);
            float h = (1.f - ec) * rcp_((1.f + eo)*(1.f + ec));     // sig(o)*tanh(cn)
            if (prow == b) h = hsL[4*mh + q8];
            Eev[mh] = h;
            sp = fmaf(qkv[mh], h, sp);
        }
        // row sum over the 4 q8 replicas -> full 64-e score for pair r
        sp += __shfl_xor(sp, 16, 64);
        sp += __shfl_xor(sp, 32, 64);
        // wave-local online softmax over the wave's 16 pairs
        float tm = sp;
        tm = fmaxf(tm, __shfl_xor(tm, 1, 64));
        tm = fmaxf(tm, __shfl_xor(tm, 2, 64));
        tm = fmaxf(tm, __shfl_xor(tm, 4, 64));
        tm = fmaxf(tm, __shfl_xor(tm, 8, 64));
        float m_new = fmaxf(m_run, tm);
        float corr = ex2(m_run - m_new);      // first tile: exp2(-inf)=0
        float wp = ex2(sp - m_new);
        l_run = fmaf(l_run, corr, wp);
        m_run = m_new;
#pragma unroll
        for (int mh = 0; mh < 16; ++mh)
            ctxa[mh] = fmaf(wp, Eev[mh], ctxa[mh]*corr);

        // ---- single barrier per tile: stage(t+1) landed, Cs reads done ----
        asm volatile("s_waitcnt vmcnt(0) lgkmcnt(0)" ::: "memory");
        __builtin_amdgcn_s_barrier();
        __builtin_amdgcn_sched_barrier(0);
    }

    // ---- epilogue: per-wave reduce over r, 4-wave merge, write partial ----
    float lred = l_run;
    lred += __shfl_xor(lred, 1, 64); lred += __shfl_xor(lred, 2, 64);
    lred += __shfl_xor(lred, 4, 64); lred += __shfl_xor(lred, 8, 64);
#pragma unroll
    for (int mh = 0; mh < 16; ++mh) {
        float v = ctxa[mh];
        v += __shfl_xor(v, 1, 64); v += __shfl_xor(v, 2, 64);
        v += __shfl_xor(v, 4, 64); v += __shfl_xor(v, 8, 64);
        if (r == 0) ctxW[w][4*mh + q8] = v;
    }
    if (l == 0) { mW[w] = m_run; lW[w] = lred; }
    __syncthreads();
    if (tid < 64) {
        float M = fmaxf(fmaxf(mW[0], mW[1]), fmaxf(mW[2], mW[3]));
        float f0 = ex2(mW[0] - M), f1 = ex2(mW[1] - M);
        float f2 = ex2(mW[2] - M), f3 = ex2(mW[3] - M);
        float csum = ctxW[0][tid]*f0 + ctxW[1][tid]*f1 + ctxW[2][tid]*f2 + ctxW[3][tid]*f3;
        float lsum = lW[0]*f0 + lW[1]*f1 + lW[2]*f2 + lW[3]*f3;
        float* pp = g_part[bh];
        pp[tid] = csum;
        if (tid == 0) { pp[64] = M; pp[65] = lsum; }
    }
}

// ---------------- merge: combine halves + fused output projection -----------
__global__ __launch_bounds__(64) void merge_kernel(float* __restrict__ out)
{
    __shared__ float ctxL[64];
    const int b = blockIdx.x, tid = threadIdx.x;
    const float* p0 = g_part[2*b];
    const float* p1 = g_part[2*b + 1];
    float m0 = p0[64], l0 = p0[65];
    float m1 = p1[64], l1 = p1[65];
    float M  = fmaxf(m0, m1);
    float f0 = ex2(m0 - M), f1 = ex2(m1 - M);
    float inv = rcp_(fmaf(l0, f0, l1 * f1));
    ctxL[tid] = (p0[tid]*f0 + p1[tid]*f1) * inv;
    __syncthreads();
    if (tid < OUTD) {
        float s = g_btot[tid];
        const float* wr2 = g_Wtot + tid*64;
        for (int k = 0; k < 64; ++k) s = fmaf(wr2[k], ctxL[k], s);
        out[b*OUTD + tid] = s;
    }
}

extern "C" void kernel_launch(void* const* d_in, const int* in_sizes, int n_in,
                              void* d_out, int out_size, void* d_ws, size_t ws_size,
                              hipStream_t stream) {
    const float* hidden = (const float*)d_in[0];
    const float* obs1   = (const float*)d_in[1];
    const float* obs2   = (const float*)d_in[2];
    const float* h0     = (const float*)d_in[3];
    const float* c0     = (const float*)d_in[4];
    const float* W_s    = (const float*)d_in[5];
    const float* b_s    = (const float*)d_in[6];
    const float* W_v    = (const float*)d_in[7];
    const float* b_v    = (const float*)d_in[8];
    const float* W_hs   = (const float*)d_in[9];
    const float* b_hs   = (const float*)d_in[10];
    const float* W_ih   = (const float*)d_in[11];
    const float* b_ih   = (const float*)d_in[12];
    const float* W_hh   = (const float*)d_in[13];
    const float* b_hh   = (const float*)d_in[14];
    const float* Wq     = (const float*)d_in[15];
    const float* Wk     = (const float*)d_in[16];
    const float* Wv     = (const float*)d_in[17];
    const float* W_in   = (const float*)d_in[18];
    const float* b_in   = (const float*)d_in[19];
    const float* W_out  = (const float*)d_in[20];
    const float* b_out  = (const float*)d_in[21];
    const float* W_o    = (const float*)d_in[22];
    const float* b_o    = (const float*)d_in[23];

    prepA<<<dim3(9), dim3(256), 0, stream>>>(
        W_ih, b_ih, W_hh, b_hh, Wq, Wk, Wv, W_in, W_hs, W_s, b_s, W_v, b_v);
    prepB<<<dim3(2 + NN), dim3(256), 0, stream>>>(
        hidden, b_hs, b_in, W_out, b_out, W_o, b_o);
    row_kernel<<<dim3(2*NN), dim3(256), 0, stream>>>(obs1, obs2, h0, c0);
    merge_kernel<<<dim3(NN), dim3(64), 0, stream>>>((float*)d_out);
}

// Round 11
// 86.949 us; speedup vs baseline: 4.1425x; 4.1425x over previous
//
#include <hip/hip_runtime.h>
#include <cstdint>

#define NN 512
#define EE 64
#define HIDD 256
#define OUTD 32
#define L2E 1.4426950408889634f

#define AS1 __attribute__((address_space(1)))
#define AS3 __attribute__((address_space(3)))

typedef __bf16 bf16x8 __attribute__((ext_vector_type(8)));
typedef __bf16 bf16x4 __attribute__((ext_vector_type(4)));
typedef float f32x4 __attribute__((ext_vector_type(4)));
typedef float f32x2 __attribute__((ext_vector_type(2)));

// -------- device-global scratch (fully rewritten every call; deterministic) --------
__device__ float g_WhsT[HIDD*EE];      // W_hs transposed [k][e]
__device__ uint4 g_Ag2[4096];          // bf16 A-frags, gate-scaled; idx = w:3|mh:1|kh:2|lane:6
__device__ float g_biasI[256];         // [e*4 + gate], gate-scaled
__device__ float g_embW[EE*4];         // per-e embed (a,b,bias,0)
__device__ float g_M2T[4096];          // [c][e]: qk matrix, (L2E/8) folded
__device__ float g_cvec[EE];
__device__ float g_Wtot[OUTD*EE];      // W_o @ W_out @ Wvc (row-major [o][k])
__device__ float g_btot[OUTD];
__device__ float g_hs[NN*EE];
__device__ float g_qk[NN*EE];

__device__ __forceinline__ float ex2(float x){ return __builtin_amdgcn_exp2f(x); }
__device__ __forceinline__ float rcp_(float x){ return __builtin_amdgcn_rcpf(x); }

// ---------------- prepA: weight packing + combined-weight chains (12 blocks) --
__global__ __launch_bounds__(256) void prepA(
    const float* __restrict__ W_ih, const float* __restrict__ b_ih,
    const float* __restrict__ W_hh, const float* __restrict__ b_hh,
    const float* __restrict__ Wq, const float* __restrict__ Wk, const float* __restrict__ Wv,
    const float* __restrict__ W_in, const float* __restrict__ W_hs,
    const float* __restrict__ W_s, const float* __restrict__ b_s,
    const float* __restrict__ W_v, const float* __restrict__ b_v,
    const float* __restrict__ b_in, const float* __restrict__ W_out,
    const float* __restrict__ b_out, const float* __restrict__ W_o,
    const float* __restrict__ b_o)
{
    __shared__ float shA[4096];
    __shared__ float shB[4096];
    __shared__ float shC[4096];
    __shared__ float shP[64*65];
    const int blk = blockIdx.x, tid = threadIdx.x;
    if (blk < 8) {
        // A-frags: wave w owns e in [8w,8w+8); e = 8w + 2*qq + mh; lane m = 4*qq+gate
#pragma unroll
        for (int ii = 0; ii < 2; ++ii) {
            int idx = blk*512 + ii*256 + tid;
            int w = idx >> 9, mh = (idx >> 8) & 1, kh = (idx >> 6) & 3, lane = idx & 63;
            int m = lane & 15, qq = m >> 2, gate = m & 3;
            int e = 8*w + 2*qq + mh;
            int o = gate*64 + e;
            int kb = kh*32 + (lane >> 4)*8;
            float sc = (gate == 2) ? (-2.f*L2E) : (-L2E);
            bf16x8 vv;
#pragma unroll
            for (int j = 0; j < 8; ++j) {
                int k = kb + j;
                float raw = (k < 64) ? W_ih[o*64 + k] : W_hh[o*64 + (k - 64)];
                vv[j] = (__bf16)(sc * raw);
            }
            g_Ag2[idx] = __builtin_bit_cast(uint4, vv);
        }
    } else if (blk == 8) {
        {
            int e = tid >> 2, gate = tid & 3, o = gate*64 + e;
            float sc = (gate == 2) ? (-2.f*L2E) : (-L2E);
            g_biasI[tid] = sc * (b_ih[o] + b_hh[o]);
        }
        if (tid < 64) {
            int e = tid;
            if (e < 32) {
                g_embW[e*4+0] = W_s[e*2]; g_embW[e*4+1] = W_s[e*2+1]; g_embW[e*4+2] = b_s[e];
            } else {
                g_embW[e*4+0] = 4.f*W_v[(e-32)*2]; g_embW[e*4+1] = 4.f*W_v[(e-32)*2+1]; g_embW[e*4+2] = b_v[e-32];
            }
            g_embW[e*4+3] = 0.f;
        }
    } else if (blk == 9) {
        // LDS-tiled transpose W_hs [64][256] -> g_WhsT [256][64]
        for (int kt = 0; kt < 4; ++kt) {
            __syncthreads();
#pragma unroll
            for (int i = 0; i < 16; ++i) {
                int row = i*4 + (tid >> 6), col = tid & 63;
                shP[col*65 + row] = W_hs[row*256 + kt*64 + col];
            }
            __syncthreads();
#pragma unroll
            for (int i = 0; i < 16; ++i) {
                int krow = i*4 + (tid >> 6), e = tid & 63;
                g_WhsT[(kt*64 + krow)*64 + e] = shP[krow*65 + e];
            }
        }
    } else if (blk == 10) {
        // Wqc = Wq2@Wq -> shB ; Wkc = Wk2@Wk -> shC ; M2T, cvec
        for (int i = tid; i < 4096; i += 256) shA[i] = Wq[i];
        __syncthreads();
        {
            const int c = tid & 63, a0 = (tid >> 6) * 16;
            for (int aa = 0; aa < 16; ++aa) {
                int a = a0 + aa;
                float s = 0.f;
                for (int m = 0; m < 64; ++m) s = fmaf(W_in[a*64 + m], shA[m*64 + c], s);
                shB[a*64 + c] = s;
            }
        }
        __syncthreads();
        for (int i = tid; i < 4096; i += 256) shA[i] = Wk[i];
        __syncthreads();
        {
            const int c = tid & 63, a0 = (tid >> 6) * 16;
            for (int aa = 0; aa < 16; ++aa) {
                int a = a0 + aa;
                float s = 0.f;
                for (int m = 0; m < 64; ++m) s = fmaf(W_in[4096 + a*64 + m], shA[m*64 + c], s);
                shC[a*64 + c] = s;
            }
        }
        __syncthreads();
        {
            const int e = tid & 63, c0b = (tid >> 6) * 16;
            for (int cc = 0; cc < 16; ++cc) {
                int c = c0b + cc;
                float s = 0.f;
                for (int a = 0; a < 64; ++a) s = fmaf(shC[a*64 + e], shB[a*64 + c], s);
                g_M2T[c*64 + e] = s * (L2E * 0.125f);
            }
        }
        if (tid < 64) {
            float s = 0.f;
            for (int a = 0; a < 64; ++a) s = fmaf(shC[a*64 + tid], b_in[a], s);
            g_cvec[tid] = s * (L2E * 0.125f);
        }
    } else {
        // Wvc = Wv2@Wv -> shB ; Wtmp = W_out@Wvc -> shC ; Wtot = W_o@Wtmp ; btot
        for (int i = tid; i < 4096; i += 256) shA[i] = Wv[i];
        __syncthreads();
        {
            const int c = tid & 63, a0 = (tid >> 6) * 16;
            for (int aa = 0; aa < 16; ++aa) {
                int a = a0 + aa;
                float s = 0.f;
                for (int m = 0; m < 64; ++m) s = fmaf(W_in[2*4096 + a*64 + m], shA[m*64 + c], s);
                shB[a*64 + c] = s;
            }
        }
        __syncthreads();
        {
            const int j = tid & 63, i0 = (tid >> 6) * 16;
            for (int ii = 0; ii < 16; ++ii) {
                int i = i0 + ii;
                float s = 0.f;
                for (int k = 0; k < 64; ++k) s = fmaf(W_out[i*64 + k], shB[k*64 + j], s);
                shC[i*64 + j] = s;
            }
        }
        if (tid < 64) {
            float s = 0.f;
            for (int k = 0; k < 64; ++k) s = fmaf(W_out[tid*64 + k], b_in[128 + k], s);
            shA[tid] = s + b_out[tid];
        }
        __syncthreads();
        for (int idx = tid; idx < OUTD*64; idx += 256) {
            int o = idx >> 6, j = idx & 63;
            float s = 0.f;
            for (int i = 0; i < 64; ++i) s = fmaf(W_o[o*64 + i], shC[i*64 + j], s);
            g_Wtot[o*64 + j] = s;
        }
        if (tid < OUTD) {
            float s = 0.f;
            for (int i = 0; i < 64; ++i) s = fmaf(W_o[tid*64 + i], shA[i], s);
            g_btot[tid] = s + b_o[tid];
        }
    }
}

// ---------------- prepB: per-row hs and qk (512 blocks x 256) ---------------
__global__ __launch_bounds__(256) void prepB(
    const float* __restrict__ hidden, const float* __restrict__ b_hs)
{
    __shared__ float hid[HIDD];
    __shared__ float partp[4][64];
    __shared__ float hsS[64];
    const int b = blockIdx.x, tid = threadIdx.x;
    hid[tid] = hidden[b*HIDD + tid];
    __syncthreads();
    const int e = tid & 63, kq = tid >> 6;
    {
        float s = 0.f;
#pragma unroll 8
        for (int k2 = 0; k2 < 64; ++k2) {
            int kk = kq*64 + k2;
            s = fmaf(g_WhsT[kk*64 + e], hid[kk], s);
        }
        partp[kq][e] = s;
    }
    __syncthreads();
    if (tid < 64) {
        float v = partp[0][tid] + partp[1][tid] + partp[2][tid] + partp[3][tid] + b_hs[tid];
        g_hs[b*64 + tid] = v;
        hsS[tid] = v;
    }
    __syncthreads();
    {
        float s = 0.f;
#pragma unroll
        for (int k2 = 0; k2 < 16; ++k2) {
            int kk = kq*16 + k2;
            s = fmaf(g_M2T[kk*64 + e], hsS[kk], s);
        }
        partp[kq][e] = s;
    }
    __syncthreads();
    if (tid < 64)
        g_qk[b*64 + tid] = partp[0][tid] + partp[1][tid] + partp[2][tid] + partp[3][tid] + g_cvec[tid];
}

// ---------------- row kernel: 512 blocks x 512 thr, 16 tiles of 32,
// double-buffered H/C staged at tile top, ONE barrier per tile, ~45KB LDS ----
__global__ __launch_bounds__(512, 4) void row_kernel(
    const float* __restrict__ obs1, const float* __restrict__ obs2,
    const float* __restrict__ h0, const float* __restrict__ c0,
    float* __restrict__ out)
{
    __shared__ __align__(16) float Hs[2][32*64];          // 16KB, swizzled 256B rows
    __shared__ __align__(16) float Cs[2][32*64];          // 16KB
    __shared__ __align__(16) unsigned short Xe[2][32*64]; // 8KB bf16, swizzled 128B rows
    __shared__ float spart[2][8][32];                     // 2KB
    __shared__ float ctxE[64];

    const int b = blockIdx.x, tid = threadIdx.x;
    const int w = tid >> 6, l = tid & 63;
    const int q = l >> 4, r = l & 15;
    const int ebase0 = 8*w + 2*q;
    const float* h0r = h0 + (size_t)b*NN*EE;
    const float* c0r = c0 + (size_t)b*NN*EE;

    auto stageT = [&](const float* gsrc, float* lbuf) {
        const int row = tid >> 4;                  // 0..31
        const int cb  = (tid & 15) * 16;
        const char* g = (const char*)gsrc + row*256 + (cb ^ ((row & 15) << 4));
        char* lp = (char*)lbuf + tid*16;
        __builtin_amdgcn_global_load_lds((const AS1 void*)g, (AS3 void*)lp, 16, 0, 0);
    };

    // ---- register hoists ----
    uint4 Afr[2][4];
#pragma unroll
    for (int mh = 0; mh < 2; ++mh)
#pragma unroll
        for (int kh = 0; kh < 4; ++kh)
            Afr[mh][kh] = g_Ag2[w*512 + mh*256 + kh*64 + l];
    f32x4 biasv[2];
#pragma unroll
    for (int mh = 0; mh < 2; ++mh) {
        float4 t4 = *(const float4*)(g_biasI + (ebase0 + mh)*4);
        biasv[mh][0]=t4.x; biasv[mh][1]=t4.y; biasv[mh][2]=t4.z; biasv[mh][3]=t4.w;
    }
    float eA[4], eB[4], eC[4];
    {
        const int e0 = (tid & 15)*4;
#pragma unroll
        for (int i = 0; i < 4; ++i) {
            eA[i] = g_embW[(e0+i)*4+0]; eB[i] = g_embW[(e0+i)*4+1]; eC[i] = g_embW[(e0+i)*4+2];
        }
    }
    const f32x2 qkr = *(const f32x2*)(g_qk + b*64 + ebase0);
    const f32x2 hsd = *(const f32x2*)(g_hs + b*64 + ebase0);
    const float ob2x = obs2[b*2], ob2y = obs2[b*2+1];
    const float ob1x = obs1[b*2], ob1y = obs1[b*2+1];
    const float velbx = ob2x - ob1x, velby = ob2y - ob1y;

    // ---- embed tile: thread = (p = tid>>4, e-quad tid&15), obs direct (broadcast) ----
    auto embedW = [&](int jb, unsigned short* xe) {
        const int p = tid >> 4;
        const float2 o2 = *(const float2*)(obs2 + 2*(jb + p));
        const float2 o1 = *(const float2*)(obs1 + 2*(jb + p));
        const float u0s = o2.x - ob2x, u1s = o2.y - ob2y;
        const float u0v = (o2.x - o1.x) - velbx, u1v = (o2.y - o1.y) - velby;
        const bool sph = ((tid & 15) < 8);
        const float u0 = sph ? u0s : u0v, u1 = sph ? u1s : u1v;
        bf16x4 pk;
#pragma unroll
        for (int i = 0; i < 4; ++i)
            pk[i] = (__bf16)fmaxf(fmaf(eA[i], u0, fmaf(eB[i], u1, eC[i])), 0.f);
        *(bf16x4*)((char*)xe + p*128 + (((tid & 15)*8) ^ ((p & 7) << 4))) = pk;
    };

    // ---- prologue: stage tile0, embed tile0, one barrier ----
    stageT(h0r, Hs[0]);
    stageT(c0r, Cs[0]);
    embedW(0, Xe[0]);
    asm volatile("s_waitcnt vmcnt(0) lgkmcnt(0)" ::: "memory");
    __builtin_amdgcn_s_barrier();
    __builtin_amdgcn_sched_barrier(0);

    float m_run = -__builtin_inff(), l_run = 0.f;
    float ctxa[2] = {0.f, 0.f};
    float Eev[2][2];

#pragma unroll 1
    for (int t = 0; t < 16; ++t) {
        const int base = t*32;
        const int cx = t & 1;

        // ---- issue next tile's stage immediately (target buf last read at t-1) ----
        if (t < 15) {
            stageT(h0r + (size_t)(t+1)*32*EE, &Hs[cx ^ 1][0]);
            stageT(c0r + (size_t)(t+1)*32*EE, &Cs[cx ^ 1][0]);
        }

        // ---- phase 1: softmax(t-1) from spart[cx^1] + Eev registers ----
        if (t > 0) {
            const int c = l & 31;
            const float* spp = &spart[cx ^ 1][0][0];
            float s_p = spp[c];
#pragma unroll
            for (int i = 1; i < 8; ++i) s_p += spp[i*32 + c];
            float tm = s_p;
#pragma unroll
            for (int off = 1; off < 32; off <<= 1) tm = fmaxf(tm, __shfl_xor(tm, off, 64));
            float m_new = fmaxf(m_run, tm);
            float corr = ex2(m_run - m_new);
            float wp = ex2(s_p - m_new);
            l_run = fmaf(l_run, corr, wp);
            m_run = m_new;
            float wn0 = __shfl(wp, r, 64);
            float wn1 = __shfl(wp, 16 + r, 64);
#pragma unroll
            for (int mh = 0; mh < 2; ++mh)
                ctxa[mh] = fmaf(wn1, Eev[mh][1], fmaf(wn0, Eev[mh][0], ctxa[mh]*corr));
        }

        // ---- phase 2: MFMA + LSTM + spart write (reads bufs of tile t) ----
        const float* HsC = &Hs[cx][0];
        const float* CsC = &Cs[cx][0];
        const unsigned short* XeC = &Xe[cx][0];
        f32x2 cpre[2];
#pragma unroll
        for (int nh = 0; nh < 2; ++nh) {
            const int p = 16*nh + r;
            cpre[nh] = *(const f32x2*)((const char*)CsC + p*256 +
                        ((ebase0*4) ^ ((p & 15) << 4)));
        }
        __builtin_amdgcn_s_setprio(1);
        f32x4 acc[2][2];
#pragma unroll
        for (int mh = 0; mh < 2; ++mh)
#pragma unroll
            for (int nh = 0; nh < 2; ++nh) acc[mh][nh] = biasv[mh];
#pragma unroll
        for (int kh = 0; kh < 4; ++kh) {
            const bf16x8 Af0 = __builtin_bit_cast(bf16x8, Afr[0][kh]);
            const bf16x8 Af1 = __builtin_bit_cast(bf16x8, Afr[1][kh]);
#pragma unroll
            for (int nh = 0; nh < 2; ++nh) {
                const int p = 16*nh + r;
                bf16x8 Bf;
                if (kh < 2) {
                    Bf = *(const bf16x8*)((const char*)XeC + p*128 +
                          ((kh*64 + q*16) ^ ((p & 7) << 4)));
                } else {
                    const char* hbp = (const char*)HsC + p*256;
                    const int cbb = (kh - 2)*128 + q*32;
                    const int sw = (p & 15) << 4;
                    f32x4 f0 = *(const f32x4*)(hbp + (cbb ^ sw));
                    f32x4 f1 = *(const f32x4*)(hbp + ((cbb + 16) ^ sw));
                    Bf[0]=(__bf16)f0[0]; Bf[1]=(__bf16)f0[1]; Bf[2]=(__bf16)f0[2]; Bf[3]=(__bf16)f0[3];
                    Bf[4]=(__bf16)f1[0]; Bf[5]=(__bf16)f1[1]; Bf[6]=(__bf16)f1[2]; Bf[7]=(__bf16)f1[3];
                }
                acc[0][nh] = __builtin_amdgcn_mfma_f32_16x16x32_bf16(Af0, Bf, acc[0][nh], 0, 0, 0);
                acc[1][nh] = __builtin_amdgcn_mfma_f32_16x16x32_bf16(Af1, Bf, acc[1][nh], 0, 0, 0);
            }
        }
        float sp[2] = {0.f, 0.f};
#pragma unroll
        for (int nh = 0; nh < 2; ++nh) {
#pragma unroll
            for (int mh = 0; mh < 2; ++mh) {
                f32x4 g4 = acc[mh][nh];           // (yi, yf, yg, yo), pre-scaled
                float ea = ex2(g4[0]);
                float eg = ex2(g4[2]);
                float itg = (1.f - eg) * rcp_((1.f + ea)*(1.f + eg));   // sig(i)*tanh(g)
                float sf = rcp_(1.f + ex2(g4[1]));
                float cn = fmaf(sf, cpre[nh][mh], itg);
                float eo = ex2(g4[3]);
                float ec = ex2(-2.f*L2E*cn);
                float h = (1.f - ec) * rcp_((1.f + eo)*(1.f + ec));     // sig(o)*tanh(cn)
                h = (16*nh + r == b - base) ? hsd[mh] : h;
                Eev[mh][nh] = h;
                sp[nh] = fmaf(qkr[mh], h, sp[nh]);
            }
        }
        __builtin_amdgcn_s_setprio(0);
#pragma unroll
        for (int nh = 0; nh < 2; ++nh) {
            float v = sp[nh];
            v += __shfl_xor(v, 16, 64);
            v += __shfl_xor(v, 32, 64);
            if (q == 0) spart[cx][w][16*nh + r] = v;
        }

        // ---- phase 3: embed(t+1) ----
        if (t < 15) embedW(base + 32, &Xe[cx ^ 1][0]);

        // ---- single barrier: spart/Xe visible, staged tile landed ----
        asm volatile("s_waitcnt vmcnt(0) lgkmcnt(0)" ::: "memory");
        __builtin_amdgcn_s_barrier();
        __builtin_amdgcn_sched_barrier(0);
    }

    // ---- final softmax (tile 15, spart[1]) ----
    {
        const int c = l & 31;
        const float* spp = &spart[1][0][0];
        float s_p = spp[c];
#pragma unroll
        for (int i = 1; i < 8; ++i) s_p += spp[i*32 + c];
        float tm = s_p;
#pragma unroll
        for (int off = 1; off < 32; off <<= 1) tm = fmaxf(tm, __shfl_xor(tm, off, 64));
        float m_new = fmaxf(m_run, tm);
        float corr = ex2(m_run - m_new);
        float wp = ex2(s_p - m_new);
        l_run = fmaf(l_run, corr, wp);
        m_run = m_new;
        float wn0 = __shfl(wp, r, 64);
        float wn1 = __shfl(wp, 16 + r, 64);
#pragma unroll
        for (int mh = 0; mh < 2; ++mh)
            ctxa[mh] = fmaf(wn1, Eev[mh][1], fmaf(wn0, Eev[mh][0], ctxa[mh]*corr));
    }

    // ---- epilogue: reduce, normalize, single fused output matvec ----
    float lred = l_run;
    lred += __shfl_xor(lred, 1, 64); lred += __shfl_xor(lred, 2, 64);
    lred += __shfl_xor(lred, 4, 64); lred += __shfl_xor(lred, 8, 64);
    lred += __shfl_xor(lred, 16, 64);
    const float inv = rcp_(lred);
#pragma unroll
    for (int mh = 0; mh < 2; ++mh) {
        float v = ctxa[mh];
        v += __shfl_xor(v, 1, 64); v += __shfl_xor(v, 2, 64);
        v += __shfl_xor(v, 4, 64); v += __shfl_xor(v, 8, 64);
        if (r == 0) ctxE[ebase0 + mh] = v * inv;
    }
    __syncthreads();
    if (tid < OUTD) {
        float s = g_btot[tid];
        const float* wr2 = g_Wtot + tid*64;
#pragma unroll 8
        for (int k = 0; k < 64; ++k) s = fmaf(wr2[k], ctxE[k], s);
        out[b*OUTD + tid] = s;
    }
}

extern "C" void kernel_launch(void* const* d_in, const int* in_sizes, int n_in,
                              void* d_out, int out_size, void* d_ws, size_t ws_size,
                              hipStream_t stream) {
    const float* hidden = (const float*)d_in[0];
    const float* obs1   = (const float*)d_in[1];
    const float* obs2   = (const float*)d_in[2];
    const float* h0     = (const float*)d_in[3];
    const float* c0     = (const float*)d_in[4];
    const float* W_s    = (const float*)d_in[5];
    const float* b_s    = (const float*)d_in[6];
    const float* W_v    = (const float*)d_in[7];
    const float* b_v    = (const float*)d_in[8];
    const float* W_hs   = (const float*)d_in[9];
    const float* b_hs   = (const float*)d_in[10];
    const float* W_ih   = (const float*)d_in[11];
    const float* b_ih   = (const float*)d_in[12];
    const float* W_hh   = (const float*)d_in[13];
    const float* b_hh   = (const float*)d_in[14];
    const float* Wq     = (const float*)d_in[15];
    const float* Wk     = (const float*)d_in[16];
    const float* Wv     = (const float*)d_in[17];
    const float* W_in   = (const float*)d_in[18];
    const float* b_in   = (const float*)d_in[19];
    const float* W_out  = (const float*)d_in[20];
    const float* b_out  = (const float*)d_in[21];
    const float* W_o    = (const float*)d_in[22];
    const float* b_o    = (const float*)d_in[23];

    prepA<<<dim3(12), dim3(256), 0, stream>>>(
        W_ih, b_ih, W_hh, b_hh, Wq, Wk, Wv, W_in, W_hs, W_s, b_s, W_v, b_v,
        b_in, W_out, b_out, W_o, b_o);
    prepB<<<dim3(NN), dim3(256), 0, stream>>>(hidden, b_hs);
    row_kernel<<<dim3(NN), dim3(512), 0, stream>>>(
        obs1, obs2, h0, c0, (float*)d_out);
}

// Round 12
// 75.695 us; speedup vs baseline: 4.7584x; 1.1487x over previous
//
#include <hip/hip_runtime.h>
#include <cstdint>

#define NN 512
#define EE 64
#define HIDD 256
#define OUTD 32
#define L2E 1.4426950408889634f

#define AS1 __attribute__((address_space(1)))
#define AS3 __attribute__((address_space(3)))

typedef __bf16 bf16x8 __attribute__((ext_vector_type(8)));
typedef __bf16 bf16x4 __attribute__((ext_vector_type(4)));
typedef float f32x4 __attribute__((ext_vector_type(4)));
typedef float f32x2 __attribute__((ext_vector_type(2)));

// -------- device-global scratch (fully rewritten every call; deterministic) --------
__device__ float g_WhsT[HIDD*EE];      // W_hs transposed [k][e]
__device__ uint4 g_Ag2[4096];          // bf16 A-frags, gate-scaled; idx = w:3|mh:1|kh:2|lane:6
__device__ float g_biasI[256];         // [e*4 + gate], gate-scaled
__device__ float g_embW[EE*4];         // per-e embed (a,b,bias,0)
__device__ float g_WqT[4096];          // Wq transposed
__device__ float g_Wq2T[4096];         // W_in rows 0-63 transposed
__device__ float g_WvT[4096];          // Wv transposed
__device__ float g_Wv2T[4096];         // W_in rows 128-191 transposed
__device__ float g_WoutT[4096];        // W_out transposed
__device__ float g_WoT[EE*OUTD];       // W_o transposed [k][o]
__device__ float g_hs[NN*EE];
__device__ float g_qk[NN*EE];

__device__ __forceinline__ float ex2(float x){ return __builtin_amdgcn_exp2f(x); }
__device__ __forceinline__ float rcp_(float x){ return __builtin_amdgcn_rcpf(x); }

// ---------------- prepA: packing + transposes ONLY (13 blocks, no matmuls) --
__global__ __launch_bounds__(256) void prepA(
    const float* __restrict__ W_ih, const float* __restrict__ b_ih,
    const float* __restrict__ W_hh, const float* __restrict__ b_hh,
    const float* __restrict__ Wq, const float* __restrict__ Wv,
    const float* __restrict__ W_in, const float* __restrict__ W_hs,
    const float* __restrict__ W_s, const float* __restrict__ b_s,
    const float* __restrict__ W_v, const float* __restrict__ b_v,
    const float* __restrict__ W_out, const float* __restrict__ W_o)
{
    __shared__ float shP[64*65];
    const int blk = blockIdx.x, tid = threadIdx.x;
    if (blk < 8) {
        // A-frags: wave w owns e in [8w,8w+8); e = 8w + 2*qq + mh; lane m = 4*qq+gate
#pragma unroll
        for (int ii = 0; ii < 2; ++ii) {
            int idx = blk*512 + ii*256 + tid;
            int w = idx >> 9, mh = (idx >> 8) & 1, kh = (idx >> 6) & 3, lane = idx & 63;
            int m = lane & 15, qq = m >> 2, gate = m & 3;
            int e = 8*w + 2*qq + mh;
            int o = gate*64 + e;
            int kb = kh*32 + (lane >> 4)*8;
            float sc = (gate == 2) ? (-2.f*L2E) : (-L2E);
            bf16x8 vv;
#pragma unroll
            for (int j = 0; j < 8; ++j) {
                int k = kb + j;
                float raw = (k < 64) ? W_ih[o*64 + k] : W_hh[o*64 + (k - 64)];
                vv[j] = (__bf16)(sc * raw);
            }
            g_Ag2[idx] = __builtin_bit_cast(uint4, vv);
        }
    } else if (blk == 8) {
        {
            int e = tid >> 2, gate = tid & 3, o = gate*64 + e;
            float sc = (gate == 2) ? (-2.f*L2E) : (-L2E);
            g_biasI[tid] = sc * (b_ih[o] + b_hh[o]);
        }
        if (tid < 64) {
            int e = tid;
            if (e < 32) {
                g_embW[e*4+0] = W_s[e*2]; g_embW[e*4+1] = W_s[e*2+1]; g_embW[e*4+2] = b_s[e];
            } else {
                g_embW[e*4+0] = 4.f*W_v[(e-32)*2]; g_embW[e*4+1] = 4.f*W_v[(e-32)*2+1]; g_embW[e*4+2] = b_v[e-32];
            }
            g_embW[e*4+3] = 0.f;
        }
    } else if (blk == 9) {
        // LDS-tiled transpose W_hs [64][256] -> g_WhsT [256][64]
        for (int kt = 0; kt < 4; ++kt) {
            __syncthreads();
#pragma unroll
            for (int i = 0; i < 16; ++i) {
                int row = i*4 + (tid >> 6), col = tid & 63;
                shP[col*65 + row] = W_hs[row*256 + kt*64 + col];
            }
            __syncthreads();
#pragma unroll
            for (int i = 0; i < 16; ++i) {
                int krow = i*4 + (tid >> 6), e = tid & 63;
                g_WhsT[(kt*64 + krow)*64 + e] = shP[krow*65 + e];
            }
        }
    } else {
        auto tr64 = [&](const float* src, float* dst) {
#pragma unroll
            for (int i = 0; i < 16; ++i) {
                int row = i*4 + (tid >> 6), col = tid & 63;
                shP[col*65 + row] = src[row*64 + col];
            }
            __syncthreads();
#pragma unroll
            for (int i = 0; i < 16; ++i) {
                int k = i*4 + (tid >> 6), e = tid & 63;
                dst[k*64 + e] = shP[k*65 + e];
            }
            __syncthreads();
        };
        if (blk == 10) {
            tr64(Wq, g_WqT);
            tr64(W_in, g_Wq2T);                 // rows 0-63 (q2)
        } else if (blk == 11) {
            tr64(Wv, g_WvT);
            tr64(W_in + 2*4096, g_Wv2T);        // rows 128-191 (v2)
        } else {
            tr64(W_out, g_WoutT);
            // W_o [32][64] -> g_WoT [64][32]
#pragma unroll
            for (int i = 0; i < 8; ++i) {
                int row = i*4 + (tid >> 6), col = tid & 63;
                shP[col*65 + row] = W_o[row*64 + col];
            }
            __syncthreads();
#pragma unroll
            for (int i = 0; i < 8; ++i) {
                int k = i*8 + (tid >> 5), o = tid & 31;
                g_WoT[k*32 + o] = shP[k*65 + o];
            }
        }
    }
}

// ---------------- prepB: per-row hs + qk chain (512 blocks x 256) -----------
__global__ __launch_bounds__(256) void prepB(
    const float* __restrict__ hidden, const float* __restrict__ b_hs,
    const float* __restrict__ W_in, const float* __restrict__ Wk,
    const float* __restrict__ b_in)
{
    __shared__ float hid[HIDD];
    __shared__ float part4[4][64];
    __shared__ float v0[64], v1[64];
    const int b = blockIdx.x, tid = threadIdx.x;
    const int e = tid & 63, kq = tid >> 6;
    hid[tid] = hidden[b*HIDD + tid];
    __syncthreads();
    {
        float s = 0.f;
#pragma unroll 8
        for (int k2 = 0; k2 < 64; ++k2) {
            int kk = kq*64 + k2;
            s = fmaf(g_WhsT[kk*64 + e], hid[kk], s);
        }
        part4[kq][e] = s;
    }
    __syncthreads();
    if (tid < 64) {
        float v = part4[0][tid] + part4[1][tid] + part4[2][tid] + part4[3][tid] + b_hs[tid];
        g_hs[b*64 + tid] = v;
        v0[tid] = v;
    }
    __syncthreads();
    auto mv = [&](const float* M, const float* vin, float* vout,
                  const float* bias, float scale) {
        float s = 0.f;
#pragma unroll
        for (int k2 = 0; k2 < 16; ++k2) {
            int kk = kq*16 + k2;
            s = fmaf(M[kk*64 + e], vin[kk], s);
        }
        part4[kq][e] = s;
        __syncthreads();
        if (tid < 64) {
            float v = bias ? bias[tid] : 0.f;
            v += part4[0][tid] + part4[1][tid] + part4[2][tid] + part4[3][tid];
            vout[tid] = v * scale;
        }
        __syncthreads();
    };
    // qk = (L2E/8) * Wk^T @ Wk2^T @ (Wq2 @ (Wq @ hs) + bq2)
    mv(g_WqT,        v0, v1, nullptr, 1.f);
    mv(g_Wq2T,       v1, v0, b_in,    1.f);
    mv(W_in + 4096,  v0, v1, nullptr, 1.f);
    mv(Wk,           v1, g_qk + b*64, nullptr, L2E*0.125f);
}

// ---------------- row kernel: 512 blocks x 512 thr, 16 tiles of 32,
// ring-3 H/C staged 2 ahead (counted vmcnt(2)), obs reg-prefetch, 1 barrier/tile
__global__ __launch_bounds__(512, 4) void row_kernel(
    const float* __restrict__ obs1, const float* __restrict__ obs2,
    const float* __restrict__ h0, const float* __restrict__ c0,
    const float* __restrict__ b_in, const float* __restrict__ b_out,
    const float* __restrict__ b_o, float* __restrict__ out)
{
    __shared__ __align__(16) float Hs[3][32*64];          // 24KB, swizzled 256B rows
    __shared__ __align__(16) float Cs[3][32*64];          // 24KB
    __shared__ __align__(16) unsigned short Xe[2][32*64]; // 8KB bf16, swizzled 128B rows
    __shared__ float spart[2][8][32];                     // 2KB
    __shared__ float part[8][64];                         // 2KB
    __shared__ float vA[64], vB[64], ctxE[64];

    const int b = blockIdx.x, tid = threadIdx.x;
    const int w = tid >> 6, l = tid & 63;
    const int q = l >> 4, r = l & 15;
    const int ebase0 = 8*w + 2*q;
    const float* h0r = h0 + (size_t)b*NN*EE;
    const float* c0r = c0 + (size_t)b*NN*EE;

    auto stageT = [&](const float* gsrc, float* lbuf) {
        const int row = tid >> 4;                  // 0..31
        const int cb  = (tid & 15) * 16;
        const char* g = (const char*)gsrc + row*256 + (cb ^ ((row & 15) << 4));
        char* lp = (char*)lbuf + tid*16;
        __builtin_amdgcn_global_load_lds((const AS1 void*)g, (AS3 void*)lp, 16, 0, 0);
    };

    // ---- obs prefetch for tile 0 (issued before stages: consumption won't drain) ----
    float2 o2n = *(const float2*)(obs2 + 2*(tid >> 4));
    float2 o1n = *(const float2*)(obs1 + 2*(tid >> 4));
    // ---- issue stages for tiles 0 and 1 ----
    stageT(h0r, &Hs[0][0]);
    stageT(c0r, &Cs[0][0]);
    stageT(h0r + 32*EE, &Hs[1][0]);
    stageT(c0r + 32*EE, &Cs[1][0]);

    // ---- register hoists ----
    uint4 Afr[2][4];
#pragma unroll
    for (int mh = 0; mh < 2; ++mh)
#pragma unroll
        for (int kh = 0; kh < 4; ++kh)
            Afr[mh][kh] = g_Ag2[w*512 + mh*256 + kh*64 + l];
    f32x4 biasv[2];
#pragma unroll
    for (int mh = 0; mh < 2; ++mh) {
        float4 t4 = *(const float4*)(g_biasI + (ebase0 + mh)*4);
        biasv[mh][0]=t4.x; biasv[mh][1]=t4.y; biasv[mh][2]=t4.z; biasv[mh][3]=t4.w;
    }
    float eA[4], eB[4], eC[4];
    {
        const int e0 = (tid & 15)*4;
#pragma unroll
        for (int i = 0; i < 4; ++i) {
            eA[i] = g_embW[(e0+i)*4+0]; eB[i] = g_embW[(e0+i)*4+1]; eC[i] = g_embW[(e0+i)*4+2];
        }
    }
    const f32x2 qkr = *(const f32x2*)(g_qk + b*64 + ebase0);
    const f32x2 hsd = *(const f32x2*)(g_hs + b*64 + ebase0);
    const float ob2x = obs2[b*2], ob2y = obs2[b*2+1];
    const float ob1x = obs1[b*2], ob1y = obs1[b*2+1];
    const float velbx = ob2x - ob1x, velby = ob2y - ob1y;

    auto embedW = [&](float2 o2, float2 o1, unsigned short* xe) {
        const int p = tid >> 4;
        const float u0s = o2.x - ob2x, u1s = o2.y - ob2y;
        const float u0v = (o2.x - o1.x) - velbx, u1v = (o2.y - o1.y) - velby;
        const bool sph = ((tid & 15) < 8);
        const float u0 = sph ? u0s : u0v, u1 = sph ? u1s : u1v;
        bf16x4 pk;
#pragma unroll
        for (int i = 0; i < 4; ++i)
            pk[i] = (__bf16)fmaxf(fmaf(eA[i], u0, fmaf(eB[i], u1, eC[i])), 0.f);
        *(bf16x4*)((char*)xe + p*128 + (((tid & 15)*8) ^ ((p & 7) << 4))) = pk;
    };

    // ---- prologue finish: embed tile0, wait tile0 staged (leave tile1 in flight) ----
    embedW(o2n, o1n, &Xe[0][0]);
    asm volatile("s_waitcnt vmcnt(2) lgkmcnt(0)" ::: "memory");
    __builtin_amdgcn_s_barrier();
    __builtin_amdgcn_sched_barrier(0);

    float m_run = -__builtin_inff(), l_run = 0.f;
    float ctxa[2] = {0.f, 0.f};
    float Eev[2][2];
    int hb = 0;

#pragma unroll 1
    for (int t = 0; t < 16; ++t) {
        const int base = t*32;
        const int cx = t & 1;

        // ---- top: obs(t+1) loads first, then stage(t+2) into ring slot ----
        if (t < 15) {
            o2n = *(const float2*)(obs2 + 2*(base + 32 + (tid >> 4)));
            o1n = *(const float2*)(obs1 + 2*(base + 32 + (tid >> 4)));
        }
        if (t < 14) {
            const int hb2 = (hb == 0) ? 2 : hb - 1;   // (hb+2)%3
            stageT(h0r + (size_t)(t+2)*32*EE, &Hs[hb2][0]);
            stageT(c0r + (size_t)(t+2)*32*EE, &Cs[hb2][0]);
        }

        // ---- phase 1: softmax(t-1) from spart[cx^1] + Eev registers ----
        if (t > 0) {
            const int c = l & 31;
            const float* spp = &spart[cx ^ 1][0][0];
            float s_p = spp[c];
#pragma unroll
            for (int i = 1; i < 8; ++i) s_p += spp[i*32 + c];
            float tm = s_p;
#pragma unroll
            for (int off = 1; off < 32; off <<= 1) tm = fmaxf(tm, __shfl_xor(tm, off, 64));
            float m_new = fmaxf(m_run, tm);
            float corr = ex2(m_run - m_new);
            float wp = ex2(s_p - m_new);
            l_run = fmaf(l_run, corr, wp);
            m_run = m_new;
            float wn0 = __shfl(wp, r, 64);
            float wn1 = __shfl(wp, 16 + r, 64);
#pragma unroll
            for (int mh = 0; mh < 2; ++mh)
                ctxa[mh] = fmaf(wn1, Eev[mh][1], fmaf(wn0, Eev[mh][0], ctxa[mh]*corr));
        }

        // ---- phase 2: MFMA + LSTM + spart write (reads ring slot hb) ----
        const float* HsC = &Hs[hb][0];
        const float* CsC = &Cs[hb][0];
        const unsigned short* XeC = &Xe[cx][0];
        f32x2 cpre[2];
#pragma unroll
        for (int nh = 0; nh < 2; ++nh) {
            const int p = 16*nh + r;
            cpre[nh] = *(const f32x2*)((const char*)CsC + p*256 +
                        ((ebase0*4) ^ ((p & 15) << 4)));
        }
        __builtin_amdgcn_s_setprio(1);
        f32x4 acc[2][2];
#pragma unroll
        for (int mh = 0; mh < 2; ++mh)
#pragma unroll
            for (int nh = 0; nh < 2; ++nh) acc[mh][nh] = biasv[mh];
#pragma unroll
        for (int kh = 0; kh < 4; ++kh) {
            const bf16x8 Af0 = __builtin_bit_cast(bf16x8, Afr[0][kh]);
            const bf16x8 Af1 = __builtin_bit_cast(bf16x8, Afr[1][kh]);
#pragma unroll
            for (int nh = 0; nh < 2; ++nh) {
                const int p = 16*nh + r;
                bf16x8 Bf;
                if (kh < 2) {
                    Bf = *(const bf16x8*)((const char*)XeC + p*128 +
                          ((kh*64 + q*16) ^ ((p & 7) << 4)));
                } else {
                    const char* hbp = (const char*)HsC + p*256;
                    const int cbb = (kh - 2)*128 + q*32;
                    const int sw = (p & 15) << 4;
                    f32x4 f0 = *(const f32x4*)(hbp + (cbb ^ sw));
                    f32x4 f1 = *(const f32x4*)(hbp + ((cbb + 16) ^ sw));
                    Bf[0]=(__bf16)f0[0]; Bf[1]=(__bf16)f0[1]; Bf[2]=(__bf16)f0[2]; Bf[3]=(__bf16)f0[3];
                    Bf[4]=(__bf16)f1[0]; Bf[5]=(__bf16)f1[1]; Bf[6]=(__bf16)f1[2]; Bf[7]=(__bf16)f1[3];
                }
                acc[0][nh] = __builtin_amdgcn_mfma_f32_16x16x32_bf16(Af0, Bf, acc[0][nh], 0, 0, 0);
                acc[1][nh] = __builtin_amdgcn_mfma_f32_16x16x32_bf16(Af1, Bf, acc[1][nh], 0, 0, 0);
            }
        }
        float sp[2] = {0.f, 0.f};
#pragma unroll
        for (int nh = 0; nh < 2; ++nh) {
#pragma unroll
            for (int mh = 0; mh < 2; ++mh) {
                f32x4 g4 = acc[mh][nh];           // (yi, yf, yg, yo), pre-scaled
                float ea = ex2(g4[0]);
                float eg = ex2(g4[2]);
                float itg = (1.f - eg) * rcp_((1.f + ea)*(1.f + eg));   // sig(i)*tanh(g)
                float sf = rcp_(1.f + ex2(g4[1]));
                float cn = fmaf(sf, cpre[nh][mh], itg);
                float eo = ex2(g4[3]);
                float ec = ex2(-2.f*L2E*cn);
                float h = (1.f - ec) * rcp_((1.f + eo)*(1.f + ec));     // sig(o)*tanh(cn)
                h = (16*nh + r == b - base) ? hsd[mh] : h;
                Eev[mh][nh] = h;
                sp[nh] = fmaf(qkr[mh], h, sp[nh]);
            }
        }
        __builtin_amdgcn_s_setprio(0);
#pragma unroll
        for (int nh = 0; nh < 2; ++nh) {
            float v = sp[nh];
            v += __shfl_xor(v, 16, 64);
            v += __shfl_xor(v, 32, 64);
            if (q == 0) spart[cx][w][16*nh + r] = v;
        }

        // ---- phase 3: embed(t+1) from prefetched obs regs ----
        if (t < 15) embedW(o2n, o1n, &Xe[cx ^ 1][0]);

        // ---- barrier: spart/Xe visible; tile t+1 staged (counted, pipe stays full) ----
        if (t < 14) {
            asm volatile("s_waitcnt vmcnt(2) lgkmcnt(0)" ::: "memory");
        } else {
            asm volatile("s_waitcnt vmcnt(0) lgkmcnt(0)" ::: "memory");
        }
        __builtin_amdgcn_s_barrier();
        __builtin_amdgcn_sched_barrier(0);
        hb = (hb == 2) ? 0 : hb + 1;
    }

    // ---- final softmax (tile 15, spart[1]) ----
    {
        const int c = l & 31;
        const float* spp = &spart[1][0][0];
        float s_p = spp[c];
#pragma unroll
        for (int i = 1; i < 8; ++i) s_p += spp[i*32 + c];
        float tm = s_p;
#pragma unroll
        for (int off = 1; off < 32; off <<= 1) tm = fmaxf(tm, __shfl_xor(tm, off, 64));
        float m_new = fmaxf(m_run, tm);
        float corr = ex2(m_run - m_new);
        float wp = ex2(s_p - m_new);
        l_run = fmaf(l_run, corr, wp);
        m_run = m_new;
        float wn0 = __shfl(wp, r, 64);
        float wn1 = __shfl(wp, 16 + r, 64);
#pragma unroll
        for (int mh = 0; mh < 2; ++mh)
            ctxa[mh] = fmaf(wn1, Eev[mh][1], fmaf(wn0, Eev[mh][0], ctxa[mh]*corr));
    }

    // ---- epilogue: reduce, normalize, chained output projection ----
    float lred = l_run;
    lred += __shfl_xor(lred, 1, 64); lred += __shfl_xor(lred, 2, 64);
    lred += __shfl_xor(lred, 4, 64); lred += __shfl_xor(lred, 8, 64);
    lred += __shfl_xor(lred, 16, 64);
    const float inv = rcp_(lred);
#pragma unroll
    for (int mh = 0; mh < 2; ++mh) {
        float v = ctxa[mh];
        v += __shfl_xor(v, 1, 64); v += __shfl_xor(v, 2, 64);
        v += __shfl_xor(v, 4, 64); v += __shfl_xor(v, 8, 64);
        if (r == 0) ctxE[ebase0 + mh] = v * inv;
    }
    __syncthreads();
    auto matvecG = [&](const float* M, const float* vin, float* vout,
                       const float* bias, float scale) {
        float s = 0.f;
#pragma unroll
        for (int k2 = 0; k2 < 8; ++k2) {
            int kk = w*8 + k2;
            s = fmaf(M[kk*64 + l], vin[kk], s);
        }
        part[w][l] = s;
        __syncthreads();
        if (tid < 64) {
            float v = bias ? bias[tid] : 0.f;
#pragma unroll
            for (int i = 0; i < 8; ++i) v += part[i][tid];
            vout[tid] = v * scale;
        }
        __syncthreads();
    };
    // out = W_o @ (W_out @ (Wv2 @ (Wv @ ctxE) + bv2) + b_out) + b_o
    matvecG(g_WvT,   ctxE, vA, nullptr,    1.f);
    matvecG(g_Wv2T,  vA,   vB, b_in + 128, 1.f);
    matvecG(g_WoutT, vB,   vA, b_out,      1.f);
    {
        if (l < 32) {
            float s = 0.f;
#pragma unroll
            for (int k2 = 0; k2 < 8; ++k2) {
                int kk = w*8 + k2;
                s = fmaf(g_WoT[kk*32 + l], vA[kk], s);
            }
            part[w][l] = s;
        }
        __syncthreads();
        if (tid < 32) {
            float v = b_o[tid];
#pragma unroll
            for (int i = 0; i < 8; ++i) v += part[i][tid];
            out[b*OUTD + tid] = v;
        }
    }
}

extern "C" void kernel_launch(void* const* d_in, const int* in_sizes, int n_in,
                              void* d_out, int out_size, void* d_ws, size_t ws_size,
                              hipStream_t stream) {
    const float* hidden = (const float*)d_in[0];
    const float* obs1   = (const float*)d_in[1];
    const float* obs2   = (const float*)d_in[2];
    const float* h0     = (const float*)d_in[3];
    const float* c0     = (const float*)d_in[4];
    const float* W_s    = (const float*)d_in[5];
    const float* b_s    = (const float*)d_in[6];
    const float* W_v    = (const float*)d_in[7];
    const float* b_v    = (const float*)d_in[8];
    const float* W_hs   = (const float*)d_in[9];
    const float* b_hs   = (const float*)d_in[10];
    const float* W_ih   = (const float*)d_in[11];
    const float* b_ih   = (const float*)d_in[12];
    const float* W_hh   = (const float*)d_in[13];
    const float* b_hh   = (const float*)d_in[14];
    const float* Wq     = (const float*)d_in[15];
    const float* Wk     = (const float*)d_in[16];
    const float* Wv     = (const float*)d_in[17];
    const float* W_in   = (const float*)d_in[18];
    const float* b_in   = (const float*)d_in[19];
    const float* W_out  = (const float*)d_in[20];
    const float* b_out  = (const float*)d_in[21];
    const float* W_o    = (const float*)d_in[22];
    const float* b_o    = (const float*)d_in[23];

    prepA<<<dim3(13), dim3(256), 0, stream>>>(
        W_ih, b_ih, W_hh, b_hh, Wq, Wv, W_in, W_hs, W_s, b_s, W_v, b_v, W_out, W_o);
    prepB<<<dim3(NN), dim3(256), 0, stream>>>(hidden, b_hs, W_in, Wk, b_in);
    row_kernel<<<dim3(NN), dim3(512), 0, stream>>>(
        obs1, obs2, h0, c0, b_in, b_out, b_o, (float*)d_out);
}